// Round 1
// baseline (360.386 us; speedup 1.0000x reference)
//
#include <hip/hip_runtime.h>
#include <hip/hip_bf16.h>

#define VOCAB 100000
#define D 300
#define B 128
#define S 2048
#define T 4

// workspace layout (float offsets)
#define WS_V      0                       // packed projection vectors [300][12]
#define WS_WTWU   3600                    // Wt@Wu [300]
#define WS_WTWO   3900                    // Wt@Wo [300][3]
#define WS_W2WO   4800                    // Wt^2@Wo [300][3]
#define WS_CONST  5700                    // b_tr dot consts [16]
#define WS_DSCAL  5716                    // per-b u0 scalars [B][8]
#define WS_U0     6740                    // u0 [B][300]
#define WS_U0W1   (WS_U0   + B*D)
#define WS_U0W2   (WS_U0W1 + B*D)
#define WS_U0W3   (WS_U0W2 + B*D)
#define WS_PROJ   (WS_U0W3 + B*D)         // proj [VOCAB][12]  (float4-aligned: offset*4 % 16 == 0)

// ---------------------------------------------------------------------------
// K1: derived vectors (Wt@Wu, Wt@Wo, Wt^2@Wo), packed V[i][12], b_tr consts.
// channels: 0=Wa 1=Wu 2=WtWu 3..5=Wo 6..8=WtWo 9..11=Wt2Wo
// consts:   0=btr.Wu 1=btr.WtWu 2..4=btr.Wo 5..7=btr.WtWo 8..10=btr.Wt2Wo
// ---------------------------------------------------------------------------
__global__ __launch_bounds__(320) void k_derive(const float* __restrict__ Watt,
                                                const float* __restrict__ Wtr,
                                                const float* __restrict__ Wout,
                                                const float* __restrict__ btr,
                                                float* __restrict__ ws) {
    int tid = threadIdx.x;
    float* V    = ws + WS_V;
    float* WtWu = ws + WS_WTWU;
    float* WtWo = ws + WS_WTWO;
    float* W2Wo = ws + WS_W2WO;
    float* cst  = ws + WS_CONST;

    if (tid < D) {
        const float* wrow = Wtr + (size_t)tid * D;
        float awu = 0.f, a0 = 0.f, a1 = 0.f, a2 = 0.f;
        for (int j = 0; j < D; ++j) {
            float w = wrow[j];
            awu += w * Watt[D + j];
            a0  += w * Wout[j * 3 + 0];
            a1  += w * Wout[j * 3 + 1];
            a2  += w * Wout[j * 3 + 2];
        }
        WtWu[tid] = awu;
        WtWo[tid * 3 + 0] = a0; WtWo[tid * 3 + 1] = a1; WtWo[tid * 3 + 2] = a2;
    }
    __syncthreads();
    if (tid < D) {
        const float* wrow = Wtr + (size_t)tid * D;
        float a0 = 0.f, a1 = 0.f, a2 = 0.f;
        for (int m = 0; m < D; ++m) {
            float w = wrow[m];
            a0 += w * WtWo[m * 3 + 0];
            a1 += w * WtWo[m * 3 + 1];
            a2 += w * WtWo[m * 3 + 2];
        }
        W2Wo[tid * 3 + 0] = a0; W2Wo[tid * 3 + 1] = a1; W2Wo[tid * 3 + 2] = a2;
    }
    __syncthreads();
    if (tid < D) {
        int i = tid;
        V[i * 12 + 0] = Watt[i];
        V[i * 12 + 1] = Watt[D + i];
        V[i * 12 + 2] = WtWu[i];
        for (int c = 0; c < 3; ++c) {
            V[i * 12 + 3 + c] = Wout[i * 3 + c];
            V[i * 12 + 6 + c] = WtWo[i * 3 + c];
            V[i * 12 + 9 + c] = W2Wo[i * 3 + c];
        }
    }
    if (tid < 11) {
        float s = 0.f;
        for (int i = 0; i < D; ++i) {
            float x;
            if      (tid == 0) x = Watt[D + i];
            else if (tid == 1) x = WtWu[i];
            else if (tid < 5)  x = Wout[i * 3 + (tid - 2)];
            else if (tid < 8)  x = WtWo[i * 3 + (tid - 5)];
            else               x = W2Wo[i * 3 + (tid - 8)];
            s += btr[i] * x;
        }
        cst[tid] = s;
    }
}

// ---------------------------------------------------------------------------
// K2: u0[b] = mean_t emb[targets[b,t]]
// ---------------------------------------------------------------------------
__global__ __launch_bounds__(320) void k_u0(const int* __restrict__ targets,
                                            const float* __restrict__ E,
                                            float* __restrict__ ws) {
    int b = blockIdx.x, i = threadIdx.x;
    if (i >= D) return;
    const int* tg = targets + b * T;
    float s = 0.f;
    for (int t = 0; t < T; ++t) s += E[(size_t)tg[t] * D + i];
    ws[WS_U0 + b * D + i] = 0.25f * s;
}

// ---------------------------------------------------------------------------
// K3: out[b] = in[b] @ Wt   (no bias)
// ---------------------------------------------------------------------------
__global__ __launch_bounds__(320) void k_matvec(const float* __restrict__ Wtr,
                                                const float* __restrict__ in,
                                                float* __restrict__ out) {
    __shared__ float row[D];
    int b = blockIdx.x, j = threadIdx.x;
    for (int i = threadIdx.x; i < D; i += blockDim.x) row[i] = in[b * D + i];
    __syncthreads();
    if (j < D) {
        float s = 0.f;
        for (int i = 0; i < D; ++i) s += row[i] * Wtr[(size_t)i * D + j];
        out[b * D + j] = s;
    }
}

// ---------------------------------------------------------------------------
// K4: per-b scalars: d0..d2 = dot(u0@Wt^h, Wu), e_c = dot(u0@Wt^3, Wo_c)
// ---------------------------------------------------------------------------
__global__ __launch_bounds__(64) void k_dscal(const float* __restrict__ Watt,
                                              const float* __restrict__ Wout,
                                              const float* __restrict__ ws,
                                              float* __restrict__ dscal) {
    int b = blockIdx.x, lane = threadIdx.x;
    const float* u0 = ws + WS_U0   + b * D;
    const float* u1 = ws + WS_U0W1 + b * D;
    const float* u2 = ws + WS_U0W2 + b * D;
    const float* u3 = ws + WS_U0W3 + b * D;
    float p0 = 0.f, p1 = 0.f, p2 = 0.f, p3 = 0.f, p4 = 0.f, p5 = 0.f;
    for (int i = lane; i < D; i += 64) {
        float wu = Watt[D + i];
        p0 += u0[i] * wu;
        p1 += u1[i] * wu;
        p2 += u2[i] * wu;
        float x3 = u3[i];
        p3 += x3 * Wout[i * 3 + 0];
        p4 += x3 * Wout[i * 3 + 1];
        p5 += x3 * Wout[i * 3 + 2];
    }
    #pragma unroll
    for (int m = 1; m < 64; m <<= 1) {
        p0 += __shfl_xor(p0, m, 64);
        p1 += __shfl_xor(p1, m, 64);
        p2 += __shfl_xor(p2, m, 64);
        p3 += __shfl_xor(p3, m, 64);
        p4 += __shfl_xor(p4, m, 64);
        p5 += __shfl_xor(p5, m, 64);
    }
    if (lane == 0) {
        float* o = dscal + b * 8;
        o[0] = p0; o[1] = p1; o[2] = p2; o[3] = p3; o[4] = p4; o[5] = p5;
    }
}

// ---------------------------------------------------------------------------
// K5: vocab projection — proj[v][k] = dot(E[v], V_k), one wave per row.
// V fragments preloaded into 60 VGPRs (fixed per-lane i-set {lane+64j}).
// ---------------------------------------------------------------------------
__global__ __launch_bounds__(256) void k_proj(const float* __restrict__ E,
                                              const float* __restrict__ Vg,
                                              float* __restrict__ proj) {
    int lane  = threadIdx.x & 63;
    int wave  = (blockIdx.x * blockDim.x + threadIdx.x) >> 6;
    int nwave = (gridDim.x * blockDim.x) >> 6;

    float v[5][12];
    #pragma unroll
    for (int j = 0; j < 5; ++j) {
        int i = lane + 64 * j;
        if (i < D) {
            const float4* p = (const float4*)(Vg + (size_t)i * 12);
            float4 a = p[0], bb = p[1], cc = p[2];
            v[j][0] = a.x;  v[j][1] = a.y;  v[j][2]  = a.z;  v[j][3]  = a.w;
            v[j][4] = bb.x; v[j][5] = bb.y; v[j][6]  = bb.z; v[j][7]  = bb.w;
            v[j][8] = cc.x; v[j][9] = cc.y; v[j][10] = cc.z; v[j][11] = cc.w;
        } else {
            #pragma unroll
            for (int k = 0; k < 12; ++k) v[j][k] = 0.f;
        }
    }

    for (int row = wave; row < VOCAB; row += nwave) {
        const float* er = E + (size_t)row * D;
        float e[5];
        #pragma unroll
        for (int j = 0; j < 5; ++j) {
            int i = lane + 64 * j;
            e[j] = (i < D) ? er[i] : 0.f;
        }
        float p[12];
        #pragma unroll
        for (int k = 0; k < 12; ++k) p[k] = 0.f;
        #pragma unroll
        for (int j = 0; j < 5; ++j) {
            #pragma unroll
            for (int k = 0; k < 12; ++k) p[k] += e[j] * v[j][k];
        }
        #pragma unroll
        for (int m = 1; m < 64; m <<= 1) {
            #pragma unroll
            for (int k = 0; k < 12; ++k) p[k] += __shfl_xor(p[k], m, 64);
        }
        if (lane == 0) {
            float4* dst = (float4*)(proj + (size_t)row * 12);
            dst[0] = make_float4(p[0], p[1], p[2],  p[3]);
            dst[1] = make_float4(p[4], p[5], p[6],  p[7]);
            dst[2] = make_float4(p[8], p[9], p[10], p[11]);
        }
    }
}

// ---------------------------------------------------------------------------
// K6: per-b hops. Each thread keeps 8 s-values x 12 channels in registers
// across all 3 hops (zero re-reads). Softmax over tanh needs no max-subtract
// (bounded arg).
// ---------------------------------------------------------------------------
__global__ __launch_bounds__(256) void k_hops(const int* __restrict__ inputs,
                                              const float* __restrict__ ws,
                                              const float* __restrict__ batt,
                                              const float* __restrict__ bout,
                                              float* __restrict__ out) {
    __shared__ float wred[4][13];
    __shared__ float sc[4];
    int b = blockIdx.x, tid = threadIdx.x, wave = tid >> 6, lane = tid & 63;
    const float* proj = ws + WS_PROJ;
    const float* cst  = ws + WS_CONST;
    const float* dsc  = ws + WS_DSCAL + b * 8;
    const int*   inp  = inputs + (size_t)b * S;

    float pv[8][12];
    #pragma unroll
    for (int q = 0; q < 8; ++q) {
        int s = tid + 256 * q;
        int idx = inp[s];
        const float4* pr = (const float4*)(proj + (size_t)idx * 12);
        float4 x = pr[0], y = pr[1], z = pr[2];
        pv[q][0] = x.x; pv[q][1] = x.y; pv[q][2]  = x.z; pv[q][3]  = x.w;
        pv[q][4] = y.x; pv[q][5] = y.y; pv[q][6]  = y.z; pv[q][7]  = y.w;
        pv[q][8] = z.x; pv[q][9] = z.y; pv[q][10] = z.z; pv[q][11] = z.w;
    }

    if (tid == 0) sc[0] = dsc[0] + batt[0];
    __syncthreads();
    float c = sc[0];

    float o3c0 = 0.f, o3c1 = 0.f, o3c2 = 0.f, uWtWu = 0.f;

    #pragma unroll
    for (int hop = 0; hop < 3; ++hop) {
        float acc[12];
        #pragma unroll
        for (int k = 0; k < 12; ++k) acc[k] = 0.f;
        #pragma unroll
        for (int q = 0; q < 8; ++q) {
            float g = tanhf(pv[q][0] + c);
            float e = __expf(g);
            acc[11] += e;
            #pragma unroll
            for (int k = 1; k < 12; ++k) acc[k - 1] += e * pv[q][k];
        }
        #pragma unroll
        for (int m = 1; m < 64; m <<= 1) {
            #pragma unroll
            for (int k = 0; k < 12; ++k) acc[k] += __shfl_xor(acc[k], m, 64);
        }
        if (lane == 0) {
            #pragma unroll
            for (int k = 0; k < 12; ++k) wred[wave][k] = acc[k];
        }
        __syncthreads();
        if (tid == 0) {
            float A[12];
            #pragma unroll
            for (int k = 0; k < 12; ++k)
                A[k] = wred[0][k] + wred[1][k] + wred[2][k] + wred[3][k];
            float inv = 1.0f / A[11];
            if (hop == 0) {
                o3c0  = A[8] * inv + dsc[3] + cst[8];
                o3c1  = A[9] * inv + dsc[4] + cst[9];
                o3c2  = A[10] * inv + dsc[5] + cst[10];
                uWtWu = A[1] * inv + dsc[2] + cst[1];
                sc[0] = A[0] * inv + dsc[1] + cst[0] + batt[0];
            } else if (hop == 1) {
                o3c0  = A[5] * inv + o3c0 + cst[5];
                o3c1  = A[6] * inv + o3c1 + cst[6];
                o3c2  = A[7] * inv + o3c2 + cst[7];
                sc[0] = A[0] * inv + uWtWu + cst[0] + batt[0];
            } else {
                out[b * 3 + 0] = A[2] * inv + o3c0 + cst[2] + bout[0];
                out[b * 3 + 1] = A[3] * inv + o3c1 + cst[3] + bout[1];
                out[b * 3 + 2] = A[4] * inv + o3c2 + cst[4] + bout[2];
            }
        }
        __syncthreads();
        c = sc[0];
    }
}

// ---------------------------------------------------------------------------
extern "C" void kernel_launch(void* const* d_in, const int* in_sizes, int n_in,
                              void* d_out, int out_size, void* d_ws, size_t ws_size,
                              hipStream_t stream) {
    const int*   inputs  = (const int*)  d_in[0];
    const int*   targets = (const int*)  d_in[1];
    const float* emb     = (const float*)d_in[2];
    const float* Watt    = (const float*)d_in[3];
    const float* batt    = (const float*)d_in[4];
    const float* Wtr     = (const float*)d_in[5];
    const float* btr     = (const float*)d_in[6];
    const float* Wout    = (const float*)d_in[7];
    const float* bout    = (const float*)d_in[8];
    float* ws  = (float*)d_ws;
    float* out = (float*)d_out;

    hipLaunchKernelGGL(k_derive, dim3(1),    dim3(320), 0, stream, Watt, Wtr, Wout, btr, ws);
    hipLaunchKernelGGL(k_proj,   dim3(2048), dim3(256), 0, stream, emb, ws + WS_V, ws + WS_PROJ);
    hipLaunchKernelGGL(k_u0,     dim3(B),    dim3(320), 0, stream, targets, emb, ws);
    hipLaunchKernelGGL(k_matvec, dim3(B),    dim3(320), 0, stream, Wtr, ws + WS_U0,   ws + WS_U0W1);
    hipLaunchKernelGGL(k_matvec, dim3(B),    dim3(320), 0, stream, Wtr, ws + WS_U0W1, ws + WS_U0W2);
    hipLaunchKernelGGL(k_matvec, dim3(B),    dim3(320), 0, stream, Wtr, ws + WS_U0W2, ws + WS_U0W3);
    hipLaunchKernelGGL(k_dscal,  dim3(B),    dim3(64),  0, stream, Watt, Wout, ws, ws + WS_DSCAL);
    hipLaunchKernelGGL(k_hops,   dim3(B),    dim3(256), 0, stream, inputs, ws, batt, bout, out);
}

// Round 4
// 255.243 us; speedup vs baseline: 1.4119x; 1.4119x over previous
//
#include <hip/hip_runtime.h>
#include <hip/hip_bf16.h>

#define VOCAB 100000
#define D 300
#define B 128
#define S 2048
#define T 4

// workspace layout (float offsets)
#define WS_V      0                    // packed projection vectors [300][12]
#define WS_WTWU   3600                 // Wt@Wu [300]
#define WS_WT2WU  3900                 // Wt^2@Wu [300]
#define WS_WTWO   4200                 // Wt@Wo [300][3]
#define WS_W2WO   5100                 // Wt^2@Wo [300][3]
#define WS_WT3WO  6000                 // Wt^3@Wo [300][3]
#define WS_CONST  6900                 // b_tr dot consts [16]
#define WS_DSCAL  6916                 // per-b u0 scalars [B][8]
#define WS_PROJ   7940                 // proj [VOCAB][12] (float4-aligned)

// channels: 0=Wa 1=Wu 2=WtWu 3..5=Wo 6..8=WtWo 9..11=Wt2Wo
// consts:   0=btr.Wu 1=btr.WtWu 2..4=btr.Wo 5..7=btr.WtWo 8..10=btr.Wt2Wo
// dscal:    0=u0.Wu 1=u0.WtWu 2=u0.Wt2Wu 3..5=u0.Wt3Wo_c

__device__ __forceinline__ float wave_red(float x) {
    #pragma unroll
    for (int m = 1; m < 64; m <<= 1) x += __shfl_xor(x, m, 64);
    return x;
}

// ---------------------------------------------------------------------------
// Level 1: WtWu[i] = Wtr[i]·Wu ; WtWo[i][c] = Wtr[i]·Wo_c.  One row per block.
// ---------------------------------------------------------------------------
__global__ __launch_bounds__(64) void k_derive1(const float* __restrict__ Watt,
                                                const float* __restrict__ Wtr,
                                                const float* __restrict__ Wout,
                                                float* __restrict__ ws) {
    int i = blockIdx.x, lane = threadIdx.x;
    const float* wrow = Wtr + (size_t)i * D;
    float au = 0.f, a0 = 0.f, a1 = 0.f, a2 = 0.f;
    for (int j = lane; j < D; j += 64) {
        float w = wrow[j];
        au += w * Watt[D + j];
        a0 += w * Wout[j * 3 + 0];
        a1 += w * Wout[j * 3 + 1];
        a2 += w * Wout[j * 3 + 2];
    }
    au = wave_red(au); a0 = wave_red(a0); a1 = wave_red(a1); a2 = wave_red(a2);
    if (lane == 0) {
        ws[WS_WTWU + i] = au;
        ws[WS_WTWO + i * 3 + 0] = a0;
        ws[WS_WTWO + i * 3 + 1] = a1;
        ws[WS_WTWO + i * 3 + 2] = a2;
    }
}

// ---------------------------------------------------------------------------
// Level 2: Wt2Wu = Wt@WtWu ; W2Wo = Wt@WtWo.
// ---------------------------------------------------------------------------
__global__ __launch_bounds__(64) void k_derive2(const float* __restrict__ Wtr,
                                                float* __restrict__ ws) {
    int i = blockIdx.x, lane = threadIdx.x;
    const float* wrow = Wtr + (size_t)i * D;
    float au = 0.f, a0 = 0.f, a1 = 0.f, a2 = 0.f;
    for (int j = lane; j < D; j += 64) {
        float w = wrow[j];
        au += w * ws[WS_WTWU + j];
        a0 += w * ws[WS_WTWO + j * 3 + 0];
        a1 += w * ws[WS_WTWO + j * 3 + 1];
        a2 += w * ws[WS_WTWO + j * 3 + 2];
    }
    au = wave_red(au); a0 = wave_red(a0); a1 = wave_red(a1); a2 = wave_red(a2);
    if (lane == 0) {
        ws[WS_WT2WU + i] = au;
        ws[WS_W2WO + i * 3 + 0] = a0;
        ws[WS_W2WO + i * 3 + 1] = a1;
        ws[WS_W2WO + i * 3 + 2] = a2;
    }
}

// ---------------------------------------------------------------------------
// Level 3: Wt3Wo = Wt@W2Wo ; pack V[i][12].
// ---------------------------------------------------------------------------
__global__ __launch_bounds__(64) void k_derive3(const float* __restrict__ Watt,
                                                const float* __restrict__ Wtr,
                                                const float* __restrict__ Wout,
                                                float* __restrict__ ws) {
    int i = blockIdx.x, lane = threadIdx.x;
    const float* wrow = Wtr + (size_t)i * D;
    float a0 = 0.f, a1 = 0.f, a2 = 0.f;
    for (int j = lane; j < D; j += 64) {
        float w = wrow[j];
        a0 += w * ws[WS_W2WO + j * 3 + 0];
        a1 += w * ws[WS_W2WO + j * 3 + 1];
        a2 += w * ws[WS_W2WO + j * 3 + 2];
    }
    a0 = wave_red(a0); a1 = wave_red(a1); a2 = wave_red(a2);
    if (lane == 0) {
        ws[WS_WT3WO + i * 3 + 0] = a0;
        ws[WS_WT3WO + i * 3 + 1] = a1;
        ws[WS_WT3WO + i * 3 + 2] = a2;
    }
    if (lane < 12) {
        float val;
        if      (lane == 0) val = Watt[i];
        else if (lane == 1) val = Watt[D + i];
        else if (lane == 2) val = ws[WS_WTWU + i];
        else if (lane < 6)  val = Wout[i * 3 + (lane - 3)];
        else if (lane < 9)  val = ws[WS_WTWO + i * 3 + (lane - 6)];
        else                val = ws[WS_W2WO + i * 3 + (lane - 9)];
        ws[WS_V + i * 12 + lane] = val;
    }
}

// ---------------------------------------------------------------------------
// k_small: blocks 0..B-1: per-b dscal from target rows (u0 never built).
//          block B: the 11 btr consts.
// ---------------------------------------------------------------------------
__global__ __launch_bounds__(64) void k_small(const int* __restrict__ targets,
                                              const float* __restrict__ E,
                                              const float* __restrict__ Watt,
                                              const float* __restrict__ Wout,
                                              const float* __restrict__ btr,
                                              float* __restrict__ ws) {
    int lane = threadIdx.x;
    if (blockIdx.x < B) {
        int b = blockIdx.x;
        int t0 = targets[b * T + 0], t1 = targets[b * T + 1];
        int t2 = targets[b * T + 2], t3 = targets[b * T + 3];
        const float* r0 = E + (size_t)t0 * D;
        const float* r1 = E + (size_t)t1 * D;
        const float* r2 = E + (size_t)t2 * D;
        const float* r3 = E + (size_t)t3 * D;
        float a0 = 0.f, a1 = 0.f, a2 = 0.f, a3 = 0.f, a4 = 0.f, a5 = 0.f;
        for (int i = lane; i < D; i += 64) {
            float u = 0.25f * (r0[i] + r1[i] + r2[i] + r3[i]);
            a0 += u * Watt[D + i];
            a1 += u * ws[WS_WTWU + i];
            a2 += u * ws[WS_WT2WU + i];
            a3 += u * ws[WS_WT3WO + i * 3 + 0];
            a4 += u * ws[WS_WT3WO + i * 3 + 1];
            a5 += u * ws[WS_WT3WO + i * 3 + 2];
        }
        a0 = wave_red(a0); a1 = wave_red(a1); a2 = wave_red(a2);
        a3 = wave_red(a3); a4 = wave_red(a4); a5 = wave_red(a5);
        if (lane == 0) {
            float* o = ws + WS_DSCAL + b * 8;
            o[0] = a0; o[1] = a1; o[2] = a2; o[3] = a3; o[4] = a4; o[5] = a5;
        }
    } else {
        float acc[11];
        #pragma unroll
        for (int k = 0; k < 11; ++k) acc[k] = 0.f;
        for (int i = lane; i < D; i += 64) {
            float bt = btr[i];
            acc[0] += bt * Watt[D + i];
            acc[1] += bt * ws[WS_WTWU + i];
            acc[2] += bt * Wout[i * 3 + 0];
            acc[3] += bt * Wout[i * 3 + 1];
            acc[4] += bt * Wout[i * 3 + 2];
            acc[5] += bt * ws[WS_WTWO + i * 3 + 0];
            acc[6] += bt * ws[WS_WTWO + i * 3 + 1];
            acc[7] += bt * ws[WS_WTWO + i * 3 + 2];
            acc[8] += bt * ws[WS_W2WO + i * 3 + 0];
            acc[9] += bt * ws[WS_W2WO + i * 3 + 1];
            acc[10] += bt * ws[WS_W2WO + i * 3 + 2];
        }
        #pragma unroll
        for (int k = 0; k < 11; ++k) acc[k] = wave_red(acc[k]);
        if (lane == 0) {
            #pragma unroll
            for (int k = 0; k < 11; ++k) ws[WS_CONST + k] = acc[k];
        }
    }
}

// ---------------------------------------------------------------------------
// K5: vocab projection — proj[v][k] = dot(E[v], V_k), one wave per row.
// ---------------------------------------------------------------------------
__global__ __launch_bounds__(256) void k_proj(const float* __restrict__ E,
                                              const float* __restrict__ Vg,
                                              float* __restrict__ proj) {
    int lane  = threadIdx.x & 63;
    int wave  = (blockIdx.x * blockDim.x + threadIdx.x) >> 6;
    int nwave = (gridDim.x * blockDim.x) >> 6;

    float v[5][12];
    #pragma unroll
    for (int j = 0; j < 5; ++j) {
        int i = lane + 64 * j;
        if (i < D) {
            const float4* p = (const float4*)(Vg + (size_t)i * 12);
            float4 a = p[0], bb = p[1], cc = p[2];
            v[j][0] = a.x;  v[j][1] = a.y;  v[j][2]  = a.z;  v[j][3]  = a.w;
            v[j][4] = bb.x; v[j][5] = bb.y; v[j][6]  = bb.z; v[j][7]  = bb.w;
            v[j][8] = cc.x; v[j][9] = cc.y; v[j][10] = cc.z; v[j][11] = cc.w;
        } else {
            #pragma unroll
            for (int k = 0; k < 12; ++k) v[j][k] = 0.f;
        }
    }

    for (int row = wave; row < VOCAB; row += nwave) {
        const float* er = E + (size_t)row * D;
        float e[5];
        #pragma unroll
        for (int j = 0; j < 5; ++j) {
            int i = lane + 64 * j;
            e[j] = (i < D) ? er[i] : 0.f;
        }
        float p[12];
        #pragma unroll
        for (int k = 0; k < 12; ++k) p[k] = 0.f;
        #pragma unroll
        for (int j = 0; j < 5; ++j) {
            #pragma unroll
            for (int k = 0; k < 12; ++k) p[k] += e[j] * v[j][k];
        }
        #pragma unroll
        for (int m = 1; m < 64; m <<= 1) {
            #pragma unroll
            for (int k = 0; k < 12; ++k) p[k] += __shfl_xor(p[k], m, 64);
        }
        if (lane == 0) {
            float4* dst = (float4*)(proj + (size_t)row * 12);
            dst[0] = make_float4(p[0], p[1], p[2],  p[3]);
            dst[1] = make_float4(p[4], p[5], p[6],  p[7]);
            dst[2] = make_float4(p[8], p[9], p[10], p[11]);
        }
    }
}

// ---------------------------------------------------------------------------
// K6: per-b hops. 512 threads, each holds 4 s-positions x 12 channels in
// registers across all 3 hops.
// ---------------------------------------------------------------------------
__global__ __launch_bounds__(512) void k_hops(const int* __restrict__ inputs,
                                              const float* __restrict__ ws,
                                              const float* __restrict__ batt,
                                              const float* __restrict__ bout,
                                              float* __restrict__ out) {
    __shared__ float wred[8][13];
    __shared__ float sc[4];
    int b = blockIdx.x, tid = threadIdx.x, wave = tid >> 6, lane = tid & 63;
    const float* proj = ws + WS_PROJ;
    const float* cst  = ws + WS_CONST;
    const float* dsc  = ws + WS_DSCAL + b * 8;
    const int*   inp  = inputs + (size_t)b * S;

    float pv[4][12];
    #pragma unroll
    for (int q = 0; q < 4; ++q) {
        int s = tid + 512 * q;
        int idx = inp[s];
        const float4* pr = (const float4*)(proj + (size_t)idx * 12);
        float4 x = pr[0], y = pr[1], z = pr[2];
        pv[q][0] = x.x; pv[q][1] = x.y; pv[q][2]  = x.z; pv[q][3]  = x.w;
        pv[q][4] = y.x; pv[q][5] = y.y; pv[q][6]  = y.z; pv[q][7]  = y.w;
        pv[q][8] = z.x; pv[q][9] = z.y; pv[q][10] = z.z; pv[q][11] = z.w;
    }

    if (tid == 0) sc[0] = dsc[0] + batt[0];
    __syncthreads();
    float c = sc[0];

    float o3c0 = 0.f, o3c1 = 0.f, o3c2 = 0.f, uWtWu = 0.f;

    #pragma unroll
    for (int hop = 0; hop < 3; ++hop) {
        float acc[12];
        #pragma unroll
        for (int k = 0; k < 12; ++k) acc[k] = 0.f;
        #pragma unroll
        for (int q = 0; q < 4; ++q) {
            float g = tanhf(pv[q][0] + c);
            float e = __expf(g);
            acc[11] += e;
            #pragma unroll
            for (int k = 1; k < 12; ++k) acc[k - 1] += e * pv[q][k];
        }
        #pragma unroll
        for (int m = 1; m < 64; m <<= 1) {
            #pragma unroll
            for (int k = 0; k < 12; ++k) acc[k] += __shfl_xor(acc[k], m, 64);
        }
        if (lane == 0) {
            #pragma unroll
            for (int k = 0; k < 12; ++k) wred[wave][k] = acc[k];
        }
        __syncthreads();
        if (tid == 0) {
            float A[12];
            #pragma unroll
            for (int k = 0; k < 12; ++k) {
                float s = 0.f;
                #pragma unroll
                for (int w = 0; w < 8; ++w) s += wred[w][k];
                A[k] = s;
            }
            float inv = 1.0f / A[11];
            if (hop == 0) {
                o3c0  = A[8] * inv + dsc[3] + cst[8];
                o3c1  = A[9] * inv + dsc[4] + cst[9];
                o3c2  = A[10] * inv + dsc[5] + cst[10];
                uWtWu = A[1] * inv + dsc[2] + cst[1];
                sc[0] = A[0] * inv + dsc[1] + cst[0] + batt[0];
            } else if (hop == 1) {
                o3c0  = A[5] * inv + o3c0 + cst[5];
                o3c1  = A[6] * inv + o3c1 + cst[6];
                o3c2  = A[7] * inv + o3c2 + cst[7];
                sc[0] = A[0] * inv + uWtWu + cst[0] + batt[0];
            } else {
                out[b * 3 + 0] = A[2] * inv + o3c0 + cst[2] + bout[0];
                out[b * 3 + 1] = A[3] * inv + o3c1 + cst[3] + bout[1];
                out[b * 3 + 2] = A[4] * inv + o3c2 + cst[4] + bout[2];
            }
        }
        __syncthreads();
        c = sc[0];
    }
}

// ---------------------------------------------------------------------------
extern "C" void kernel_launch(void* const* d_in, const int* in_sizes, int n_in,
                              void* d_out, int out_size, void* d_ws, size_t ws_size,
                              hipStream_t stream) {
    const int*   inputs  = (const int*)  d_in[0];
    const int*   targets = (const int*)  d_in[1];
    const float* emb     = (const float*)d_in[2];
    const float* Watt    = (const float*)d_in[3];
    const float* batt    = (const float*)d_in[4];
    const float* Wtr     = (const float*)d_in[5];
    const float* btr     = (const float*)d_in[6];
    const float* Wout    = (const float*)d_in[7];
    const float* bout    = (const float*)d_in[8];
    float* ws  = (float*)d_ws;
    float* out = (float*)d_out;

    hipLaunchKernelGGL(k_derive1, dim3(D),    dim3(64),  0, stream, Watt, Wtr, Wout, ws);
    hipLaunchKernelGGL(k_derive2, dim3(D),    dim3(64),  0, stream, Wtr, ws);
    hipLaunchKernelGGL(k_derive3, dim3(D),    dim3(64),  0, stream, Watt, Wtr, Wout, ws);
    hipLaunchKernelGGL(k_proj,    dim3(2048), dim3(256), 0, stream, emb, ws + WS_V, ws + WS_PROJ);
    hipLaunchKernelGGL(k_small,   dim3(B + 1), dim3(64), 0, stream, targets, emb, Watt, Wout, btr, ws);
    hipLaunchKernelGGL(k_hops,    dim3(B),    dim3(512), 0, stream, inputs, ws, batt, bout, out);
}

// Round 6
// 235.854 us; speedup vs baseline: 1.5280x; 1.0822x over previous
//
#include <hip/hip_runtime.h>
#include <hip/hip_bf16.h>

#define VOCAB 100000
#define D 300
#define B 128
#define S 2048
#define T 4

// workspace layout (float offsets)
#define WS_V      0                    // packed projection vectors [300][12]
#define WS_WTWU   3600                 // Wt@Wu [300]
#define WS_WT2WU  3900                 // Wt^2@Wu [300]
#define WS_WTWO   4200                 // Wt@Wo [300][3]
#define WS_W2WO   5100                 // Wt^2@Wo [300][3]
#define WS_WT3WO  6000                 // Wt^3@Wo [300][3]
#define WS_CONST  6900                 // b_tr dot consts [16]
#define WS_DSCAL  6916                 // per-b u0 scalars [B][8]
#define WS_PROJ   7940                 // proj [VOCAB][12] (float4-aligned)

// channels: 0=Wa 1=Wu 2=WtWu 3..5=Wo 6..8=WtWo 9..11=Wt2Wo
// consts:   0=btr.Wu 1=btr.WtWu 2..4=btr.Wo 5..7=btr.WtWo 8..10=btr.Wt2Wo
// dscal:    0=u0.Wu 1=u0.WtWu 2=u0.Wt2Wu 3..5=u0.Wt3Wo_c

__device__ __forceinline__ float wave_red(float x) {
    #pragma unroll
    for (int m = 1; m < 64; m <<= 1) x += __shfl_xor(x, m, 64);
    return x;
}

// ---------------------------------------------------------------------------
// Level 1: WtWu[i] = Wtr[i]·Wu ; WtWo[i][c] = Wtr[i]·Wo_c.  One row per block.
// ---------------------------------------------------------------------------
__global__ __launch_bounds__(64) void k_derive1(const float* __restrict__ Watt,
                                                const float* __restrict__ Wtr,
                                                const float* __restrict__ Wout,
                                                float* __restrict__ ws) {
    int i = blockIdx.x, lane = threadIdx.x;
    const float* wrow = Wtr + (size_t)i * D;
    float au = 0.f, a0 = 0.f, a1 = 0.f, a2 = 0.f;
    for (int j = lane; j < D; j += 64) {
        float w = wrow[j];
        au += w * Watt[D + j];
        a0 += w * Wout[j * 3 + 0];
        a1 += w * Wout[j * 3 + 1];
        a2 += w * Wout[j * 3 + 2];
    }
    au = wave_red(au); a0 = wave_red(a0); a1 = wave_red(a1); a2 = wave_red(a2);
    if (lane == 0) {
        ws[WS_WTWU + i] = au;
        ws[WS_WTWO + i * 3 + 0] = a0;
        ws[WS_WTWO + i * 3 + 1] = a1;
        ws[WS_WTWO + i * 3 + 2] = a2;
    }
}

// ---------------------------------------------------------------------------
// Level 2: Wt2Wu = Wt@WtWu ; W2Wo = Wt@WtWo.
// ---------------------------------------------------------------------------
__global__ __launch_bounds__(64) void k_derive2(const float* __restrict__ Wtr,
                                                float* __restrict__ ws) {
    int i = blockIdx.x, lane = threadIdx.x;
    const float* wrow = Wtr + (size_t)i * D;
    float au = 0.f, a0 = 0.f, a1 = 0.f, a2 = 0.f;
    for (int j = lane; j < D; j += 64) {
        float w = wrow[j];
        au += w * ws[WS_WTWU + j];
        a0 += w * ws[WS_WTWO + j * 3 + 0];
        a1 += w * ws[WS_WTWO + j * 3 + 1];
        a2 += w * ws[WS_WTWO + j * 3 + 2];
    }
    au = wave_red(au); a0 = wave_red(a0); a1 = wave_red(a1); a2 = wave_red(a2);
    if (lane == 0) {
        ws[WS_WT2WU + i] = au;
        ws[WS_W2WO + i * 3 + 0] = a0;
        ws[WS_W2WO + i * 3 + 1] = a1;
        ws[WS_W2WO + i * 3 + 2] = a2;
    }
}

// ---------------------------------------------------------------------------
// Level 3: Wt3Wo = Wt@W2Wo ; pack V[i][12].
// ---------------------------------------------------------------------------
__global__ __launch_bounds__(64) void k_derive3(const float* __restrict__ Watt,
                                                const float* __restrict__ Wtr,
                                                const float* __restrict__ Wout,
                                                float* __restrict__ ws) {
    int i = blockIdx.x, lane = threadIdx.x;
    const float* wrow = Wtr + (size_t)i * D;
    float a0 = 0.f, a1 = 0.f, a2 = 0.f;
    for (int j = lane; j < D; j += 64) {
        float w = wrow[j];
        a0 += w * ws[WS_W2WO + j * 3 + 0];
        a1 += w * ws[WS_W2WO + j * 3 + 1];
        a2 += w * ws[WS_W2WO + j * 3 + 2];
    }
    a0 = wave_red(a0); a1 = wave_red(a1); a2 = wave_red(a2);
    if (lane == 0) {
        ws[WS_WT3WO + i * 3 + 0] = a0;
        ws[WS_WT3WO + i * 3 + 1] = a1;
        ws[WS_WT3WO + i * 3 + 2] = a2;
    }
    if (lane < 12) {
        float val;
        if      (lane == 0) val = Watt[i];
        else if (lane == 1) val = Watt[D + i];
        else if (lane == 2) val = ws[WS_WTWU + i];
        else if (lane < 6)  val = Wout[i * 3 + (lane - 3)];
        else if (lane < 9)  val = ws[WS_WTWO + i * 3 + (lane - 6)];
        else                val = ws[WS_W2WO + i * 3 + (lane - 9)];
        ws[WS_V + i * 12 + lane] = val;
    }
}

// ---------------------------------------------------------------------------
// k_small: blocks 0..B-1: per-b dscal from target rows (u0 never built).
//          block B: the 11 btr consts.
// ---------------------------------------------------------------------------
__global__ __launch_bounds__(64) void k_small(const int* __restrict__ targets,
                                              const float* __restrict__ E,
                                              const float* __restrict__ Watt,
                                              const float* __restrict__ Wout,
                                              const float* __restrict__ btr,
                                              float* __restrict__ ws) {
    int lane = threadIdx.x;
    if (blockIdx.x < B) {
        int b = blockIdx.x;
        int t0 = targets[b * T + 0], t1 = targets[b * T + 1];
        int t2 = targets[b * T + 2], t3 = targets[b * T + 3];
        const float* r0 = E + (size_t)t0 * D;
        const float* r1 = E + (size_t)t1 * D;
        const float* r2 = E + (size_t)t2 * D;
        const float* r3 = E + (size_t)t3 * D;
        float a0 = 0.f, a1 = 0.f, a2 = 0.f, a3 = 0.f, a4 = 0.f, a5 = 0.f;
        for (int i = lane; i < D; i += 64) {
            float u = 0.25f * (r0[i] + r1[i] + r2[i] + r3[i]);
            a0 += u * Watt[D + i];
            a1 += u * ws[WS_WTWU + i];
            a2 += u * ws[WS_WT2WU + i];
            a3 += u * ws[WS_WT3WO + i * 3 + 0];
            a4 += u * ws[WS_WT3WO + i * 3 + 1];
            a5 += u * ws[WS_WT3WO + i * 3 + 2];
        }
        a0 = wave_red(a0); a1 = wave_red(a1); a2 = wave_red(a2);
        a3 = wave_red(a3); a4 = wave_red(a4); a5 = wave_red(a5);
        if (lane == 0) {
            float* o = ws + WS_DSCAL + b * 8;
            o[0] = a0; o[1] = a1; o[2] = a2; o[3] = a3; o[4] = a4; o[5] = a5;
        }
    } else {
        float acc[11];
        #pragma unroll
        for (int k = 0; k < 11; ++k) acc[k] = 0.f;
        for (int i = lane; i < D; i += 64) {
            float bt = btr[i];
            acc[0] += bt * Watt[D + i];
            acc[1] += bt * ws[WS_WTWU + i];
            acc[2] += bt * Wout[i * 3 + 0];
            acc[3] += bt * Wout[i * 3 + 1];
            acc[4] += bt * Wout[i * 3 + 2];
            acc[5] += bt * ws[WS_WTWO + i * 3 + 0];
            acc[6] += bt * ws[WS_WTWO + i * 3 + 1];
            acc[7] += bt * ws[WS_WTWO + i * 3 + 2];
            acc[8] += bt * ws[WS_W2WO + i * 3 + 0];
            acc[9] += bt * ws[WS_W2WO + i * 3 + 1];
            acc[10] += bt * ws[WS_W2WO + i * 3 + 2];
        }
        #pragma unroll
        for (int k = 0; k < 11; ++k) acc[k] = wave_red(acc[k]);
        if (lane == 0) {
            #pragma unroll
            for (int k = 0; k < 11; ++k) ws[WS_CONST + k] = acc[k];
        }
    }
}

// ---------------------------------------------------------------------------
// K5: vocab projection, row-per-lane. Lane r owns row wid*64+r: reads it as
// 75 float4 (sequential per lane -> every 64B line fully consumed via L1),
// V operand is wave-uniform -> scalar loads + SGPR FMA operand. No shuffles,
// no LDS, coalesced-by-line stores (adjacent lanes -> adjacent 48B rows).
// ---------------------------------------------------------------------------
__global__ __launch_bounds__(256) void k_proj(const float* __restrict__ E,
                                              const float* __restrict__ Vg,
                                              float* __restrict__ proj) {
    int lane = threadIdx.x & 63;
    int wid  = (blockIdx.x * blockDim.x + threadIdx.x) >> 6;
    int row  = wid * 64 + lane;
    if (row >= VOCAB) return;

    const float4* er = (const float4*)(E + (size_t)row * D);   // 75 float4
    float acc[12];
    #pragma unroll
    for (int c = 0; c < 12; ++c) acc[c] = 0.f;

    #pragma unroll 5
    for (int k4 = 0; k4 < 75; ++k4) {
        float4 e = er[k4];
        const float* vp = Vg + k4 * 48;            // 4 k-rows of V, uniform
        #pragma unroll
        for (int c = 0; c < 12; ++c) {
            acc[c] += e.x * vp[c];
            acc[c] += e.y * vp[12 + c];
            acc[c] += e.z * vp[24 + c];
            acc[c] += e.w * vp[36 + c];
        }
    }

    float4* dst = (float4*)(proj + (size_t)row * 12);
    dst[0] = make_float4(acc[0], acc[1], acc[2],  acc[3]);
    dst[1] = make_float4(acc[4], acc[5], acc[6],  acc[7]);
    dst[2] = make_float4(acc[8], acc[9], acc[10], acc[11]);
}

// ---------------------------------------------------------------------------
// K6: per-b hops. 1024 threads (16 waves -> 4/SIMD gather-latency hiding),
// each thread holds 2 s-positions x 12 channels in registers across 3 hops.
// ---------------------------------------------------------------------------
__global__ __launch_bounds__(1024) void k_hops(const int* __restrict__ inputs,
                                               const float* __restrict__ ws,
                                               const float* __restrict__ batt,
                                               const float* __restrict__ bout,
                                               float* __restrict__ out) {
    __shared__ float wred[16][13];
    __shared__ float Ash[13];
    __shared__ float sc[4];
    int b = blockIdx.x, tid = threadIdx.x, wave = tid >> 6, lane = tid & 63;
    const float* proj = ws + WS_PROJ;
    const float* cst  = ws + WS_CONST;
    const float* dsc  = ws + WS_DSCAL + b * 8;
    const int*   inp  = inputs + (size_t)b * S;

    float pv[2][12];
    #pragma unroll
    for (int q = 0; q < 2; ++q) {
        int s = tid + 1024 * q;
        int idx = inp[s];
        const float4* pr = (const float4*)(proj + (size_t)idx * 12);
        float4 x = pr[0], y = pr[1], z = pr[2];
        pv[q][0] = x.x; pv[q][1] = x.y; pv[q][2]  = x.z; pv[q][3]  = x.w;
        pv[q][4] = y.x; pv[q][5] = y.y; pv[q][6]  = y.z; pv[q][7]  = y.w;
        pv[q][8] = z.x; pv[q][9] = z.y; pv[q][10] = z.z; pv[q][11] = z.w;
    }

    if (tid == 0) sc[0] = dsc[0] + batt[0];
    __syncthreads();
    float c = sc[0];

    float o3c0 = 0.f, o3c1 = 0.f, o3c2 = 0.f, uWtWu = 0.f;

    #pragma unroll
    for (int hop = 0; hop < 3; ++hop) {
        float acc[12];
        #pragma unroll
        for (int k = 0; k < 12; ++k) acc[k] = 0.f;
        #pragma unroll
        for (int q = 0; q < 2; ++q) {
            float g = tanhf(pv[q][0] + c);
            float e = __expf(g);
            acc[11] += e;
            #pragma unroll
            for (int k = 1; k < 12; ++k) acc[k - 1] += e * pv[q][k];
        }
        #pragma unroll
        for (int m = 1; m < 64; m <<= 1) {
            #pragma unroll
            for (int k = 0; k < 12; ++k) acc[k] += __shfl_xor(acc[k], m, 64);
        }
        if (lane == 0) {
            #pragma unroll
            for (int k = 0; k < 12; ++k) wred[wave][k] = acc[k];
        }
        __syncthreads();
        if (tid < 12) {
            float s = 0.f;
            #pragma unroll
            for (int w = 0; w < 16; ++w) s += wred[w][tid];
            Ash[tid] = s;
        }
        __syncthreads();
        if (tid == 0) {
            float inv = 1.0f / Ash[11];
            if (hop == 0) {
                o3c0  = Ash[8] * inv + dsc[3] + cst[8];
                o3c1  = Ash[9] * inv + dsc[4] + cst[9];
                o3c2  = Ash[10] * inv + dsc[5] + cst[10];
                uWtWu = Ash[1] * inv + dsc[2] + cst[1];
                sc[0] = Ash[0] * inv + dsc[1] + cst[0] + batt[0];
            } else if (hop == 1) {
                o3c0  = Ash[5] * inv + o3c0 + cst[5];
                o3c1  = Ash[6] * inv + o3c1 + cst[6];
                o3c2  = Ash[7] * inv + o3c2 + cst[7];
                sc[0] = Ash[0] * inv + uWtWu + cst[0] + batt[0];
            } else {
                out[b * 3 + 0] = Ash[2] * inv + o3c0 + cst[2] + bout[0];
                out[b * 3 + 1] = Ash[3] * inv + o3c1 + cst[3] + bout[1];
                out[b * 3 + 2] = Ash[4] * inv + o3c2 + cst[4] + bout[2];
            }
        }
        __syncthreads();
        c = sc[0];
    }
}

// ---------------------------------------------------------------------------
extern "C" void kernel_launch(void* const* d_in, const int* in_sizes, int n_in,
                              void* d_out, int out_size, void* d_ws, size_t ws_size,
                              hipStream_t stream) {
    const int*   inputs  = (const int*)  d_in[0];
    const int*   targets = (const int*)  d_in[1];
    const float* emb     = (const float*)d_in[2];
    const float* Watt    = (const float*)d_in[3];
    const float* batt    = (const float*)d_in[4];
    const float* Wtr     = (const float*)d_in[5];
    const float* btr     = (const float*)d_in[6];
    const float* Wout    = (const float*)d_in[7];
    const float* bout    = (const float*)d_in[8];
    float* ws  = (float*)d_ws;
    float* out = (float*)d_out;

    // 100000 rows / (4 waves * 64 rows) per block -> 391 blocks
    hipLaunchKernelGGL(k_derive1, dim3(D),    dim3(64),   0, stream, Watt, Wtr, Wout, ws);
    hipLaunchKernelGGL(k_derive2, dim3(D),    dim3(64),   0, stream, Wtr, ws);
    hipLaunchKernelGGL(k_derive3, dim3(D),    dim3(64),   0, stream, Watt, Wtr, Wout, ws);
    hipLaunchKernelGGL(k_proj,    dim3(391),  dim3(256),  0, stream, emb, ws + WS_V, ws + WS_PROJ);
    hipLaunchKernelGGL(k_small,   dim3(B + 1), dim3(64),  0, stream, targets, emb, Watt, Wout, btr, ws);
    hipLaunchKernelGGL(k_hops,    dim3(B),    dim3(1024), 0, stream, inputs, ws, batt, bout, out);
}